// Round 8
// baseline (321.640 us; speedup 1.0000x reference)
//
#include <hip/hip_runtime.h>
#include <stdint.h>

typedef unsigned long long u64;
typedef float vf4 __attribute__((ext_vector_type(4)));

#define NB 32
#define N 512
#define MAXD 10
#define NW 8    // u64 words per 512-bit row
#define ST 516  // adjT plane stride in u64: 2-way write banks (free), was 8-way at 512
#define PB 8    // frontier pops per batch: 64 independent ds_read_b64 in flight
#define SRC 16  // sources per block (K2): 1024 blocks -> 4 blocks/CU TLP

// ---------------- K1: binarize + symmetrize + mask -> packed bitset (bit-domain) ----------------
// 4.6 us measured (round-7 delta) ~= 32 MiB read floor. DONE — unchanged.
__global__ __launch_bounds__(256) void k1_pack(const float* __restrict__ adj,
                                               const int* __restrict__ mask,
                                               u64* __restrict__ gsym) {
    __shared__ u64 pa[64];   // packed bits of A(i0+r, j0+c): bit c of pa[r]
    __shared__ u64 pb[64];   // packed bits of A(j0+r, i0+c)
    __shared__ u64 mwIJ[2];  // packed node-mask words for row-blocks ti, tj
    int p = blockIdx.x;
    int b = blockIdx.y;
    int ti = 0;
    while (p >= 8 - ti) { p -= 8 - ti; ++ti; }
    int tj = ti + p;
    int i0 = ti * 64, j0 = tj * 64;
    int t = threadIdx.x, wave = t >> 6, lane = t & 63;
    const float* Ab = adj + (size_t)b * N * N;
    // phase 1: ballot-pack. wave w handles rows w*16..w*16+15 of both tiles.
    #pragma unroll 4
    for (int s = 0; s < 16; ++s) {
        int r = wave * 16 + s;
        bool ba = Ab[(size_t)(i0 + r) * N + j0 + lane] > 0.5f;   // 256 B coalesced
        u64 wa = __ballot(ba);
        bool bb = Ab[(size_t)(j0 + r) * N + i0 + lane] > 0.5f;
        u64 wb = __ballot(bb);
        if (lane == 0) { pa[r] = wa; pb[r] = wb; }
    }
    if (wave < 2) {  // packed mask words (node_mask arrives as int32)
        u64 m = __ballot(mask[b * N + (wave == 0 ? i0 : j0) + lane] != 0);
        if (lane == 0) mwIJ[wave] = m;
    }
    __syncthreads();

    if (wave < 2) {
        // wave0 -> S(ti,tj) = pa | pb^T ; wave1 -> S(tj,ti) = pb | pa^T
        u64 x = (wave == 0) ? pb[lane] : pa[lane];
        // 64x64 bit transpose across the wave: recursive block swap, 6 stages.
        const u64 Hm[6] = {0xFFFFFFFF00000000ULL, 0xFFFF0000FFFF0000ULL,
                           0xFF00FF00FF00FF00ULL, 0xF0F0F0F0F0F0F0F0ULL,
                           0xCCCCCCCCCCCCCCCCULL, 0xAAAAAAAAAAAAAAAAULL};
        #pragma unroll
        for (int k = 0; k < 6; ++k) {
            int j = 32 >> k;
            u64 H = Hm[k];
            u64 y = (u64)__shfl_xor((unsigned long long)x, j);
            x = ((lane & j) == 0) ? ((x & ~H) | ((y << j) & H))
                                  : ((x & H) | ((y >> j) & ~H));
        }
        u64 own  = (wave == 0) ? pa[lane] : pb[lane];
        u64 mrow = mwIJ[wave];           // validity of this output row block
        u64 mcol = mwIJ[wave ^ 1];       // packed mask of the column block
        u64 outw = (own | x) & (((mrow >> lane) & 1) ? mcol : 0ULL);
        size_t row = (size_t)b * N + (wave == 0 ? i0 : j0) + lane;
        int wt = (wave == 0) ? tj : ti;
        gsym[row * NW + wt] = outw;      // diagonal pairs: identical double write, benign
    }
}

// spread 8 bits -> u64 of 8 bytes each 0/1
__device__ __forceinline__ u64 spread8(unsigned b) {
    u64 x = (u64)(b * 0x01010101u);
    x |= x << 32;                       // broadcast byte to all 8 byte lanes
    x &= 0x8040201008040201ULL;         // byte i keeps bit i
    x += 0x7f7f7f7f7f7f7f7fULL;         // bit7 of byte i = (bit i was set); no cross-byte carry
    return (x >> 7) & 0x0101010101010101ULL;
}

// ---------------- K2 v3: bitset-BFS -> dist bytes in global ws ----------------
// Round-7 ledger: K2 = 14.9 us vs ~5 us model. Theory: 1 block/CU + wave0-only
// BFS/expand = no TLP over the latency/serial path; k=1 batch wastes 8x reads;
// outB round-trip adds a full LDS pass. Fixes: (1) 1024 blocks x 16 sources ->
// 4 blocks/CU (LDS 37 KB); (2) k=1 direct row read (8 reads); (3) counters
// dumped to LDS (4 KB), all 256 threads expand+store directly (no outB).
// Predicted K2 ~6 us.
__global__ __launch_bounds__(256) void k2_bfs(const u64* __restrict__ gsym,
                                              const int* __restrict__ mask,
                                              u64* __restrict__ distw) {
    __shared__ u64 adjT[NW * ST];        // 33 KB, plane-major [w][j], padded stride
    __shared__ u64 cd[SRC][NW][4];       // 4 KB: bit-sliced counters [source][word][plane]
    int blk = blockIdx.x;
    int b = blk >> 5;
    int r0 = (blk & 31) * SRC;
    int t = threadIdx.x;
    const u64* gs = gsym + (size_t)b * N * NW;
    for (int q = t; q < N * NW; q += 256) {
        adjT[(q & 7) * ST + (q >> 3)] = gs[q];   // coalesced read; padded-stride transpose
    }
    __syncthreads();

    if (t < SRC) {
        int i = r0 + t;
        bool mi = mask[b * N + i] != 0;
        u64 c0[NW], c1[NW], c2[NW], c3[NW];
        #pragma unroll
        for (int w = 0; w < NW; ++w) { c0[w] = 0; c1[w] = 0; c2[w] = 0; c3[w] = 0; }

        if (mi) {
            u64 reach[NW] = {};
            u64 frontier[NW] = {};
            reach[i >> 6] = 1ULL << (i & 63);
            bool active = true;
            for (int k = 0; k <= MAXD; ++k) {
                // c += ~reach  (bit-sliced increment, 4-bit, max value 11)
                u64 nr_any = 0;
                #pragma unroll
                for (int w = 0; w < NW; ++w) {
                    u64 u = ~reach[w];
                    nr_any |= u;
                    u64 t0 = c0[w] & u; c0[w] ^= u;
                    u64 t1 = c1[w] & t0; c1[w] ^= t0;
                    u64 t2 = c2[w] & t1; c2[w] ^= t1;
                    c3[w] ^= t2;
                }
                if (nr_any == 0) break;   // reach full: all remaining increments no-op
                if (k == MAXD) break;
                if (active) {
                    u64 acc[NW];
                    bool sat = false;
                    if (k == 0) {
                        // frontier = {self}: the expansion is just row i. 8 reads, no batch waste.
                        #pragma unroll
                        for (int e = 0; e < NW; ++e) acc[e] = adjT[e * ST + i];
                    } else {
                        #pragma unroll
                        for (int e = 0; e < NW; ++e) acc[e] = 0;
                        for (int w = 0; w < NW && !sat; ++w) {
                            u64 f = frontier[w];
                            while (f && !sat) {
                                // batched pops: up to PB bits, 64 independent ds_read_b64, one check
                                int jlast = w << 6;
                                #pragma unroll
                                for (int u = 0; u < PB; ++u) {
                                    int j = f ? ((w << 6) + __builtin_ctzll(f)) : jlast;
                                    jlast = j;
                                    f &= f - 1;                  // stays 0 once empty
                                    #pragma unroll
                                    for (int e = 0; e < NW; ++e) acc[e] |= adjT[e * ST + j];
                                }
                                u64 all = acc[0];
                                #pragma unroll
                                for (int e = 1; e < NW; ++e) all &= acc[e];
                                sat = (all == ~0ULL);            // union saturated: exact
                            }
                        }
                    }
                    bool any = false;
                    #pragma unroll
                    for (int w = 0; w < NW; ++w) {
                        u64 nf = acc[w] & ~reach[w];
                        frontier[w] = nf;
                        reach[w] |= nf;
                        any = any || (nf != 0);
                    }
                    active = any;
                }
            }
        } else {
            // invalid source row: all distances = 11 = 0b1011
            #pragma unroll
            for (int w = 0; w < NW; ++w) { c0[w] = ~0ULL; c1[w] = ~0ULL; c3[w] = ~0ULL; }
        }

        // dump bit-sliced counters to LDS for the all-thread expansion
        #pragma unroll
        for (int w = 0; w < NW; ++w) {
            cd[t][w][0] = c0[w];
            cd[t][w][1] = c1[w];
            cd[t][w][2] = c2[w];
            cd[t][w][3] = c3[w];
        }
    }
    __syncthreads();

    // all 256 threads: expand counters -> dist bytes, store straight to global.
    // q = s*64 + v over [0, SRC*64): byte h of word w of source s needs byte h of
    // cd[s][w][0..3]. Stores are lane-consecutive u64 (2 KB per wave-instr).
    const unsigned char* cb = (const unsigned char*)cd;
    u64* dp = distw + ((size_t)(b * N + r0)) * 64;  // 64 u64 words per 512-byte row
    #pragma unroll
    for (int g = 0; g < (SRC * 64) / 256; ++g) {    // 4 iterations
        int q = t + 256 * g;
        int s = q >> 6, v = q & 63, w = v >> 3, h = v & 7;
        int base = ((s * NW + w) * 4) * 8 + h;
        unsigned b0 = cb[base];
        unsigned b1 = cb[base + 8];
        unsigned b2 = cb[base + 16];
        unsigned b3 = cb[base + 24];
        dp[q] = spread8(b0) | (spread8(b1) << 1) | (spread8(b2) << 2) | (spread8(b3) << 3);
    }
}

// ---------------- K3: pure streaming expansion dist byte -> 2x vf4 ----------------
// UNCHANGED — proven at the 6.3 TB/s write roofline (41.6 us, probe rounds 3+4).
__global__ __launch_bounds__(256) void k3_expand(const u64* __restrict__ distw,
                                                 const float* __restrict__ emb,
                                                 vf4* __restrict__ out4) {
    __shared__ vf4 e4[(MAXD + 2) * 2];
    int t = threadIdx.x;
    if (t < (MAXD + 2) * 2) e4[t] = ((const vf4*)emb)[t];
    __syncthreads();
    const unsigned char* __restrict__ db = (const unsigned char*)distw;
    size_t dbase = (size_t)blockIdx.x * 4096;     // dist bytes per block
    const unsigned char* dp = db + dbase;
    vf4* op = out4 + dbase * 2;
    int h = t & 1;
    int tb = t >> 1;
    #pragma unroll 8
    for (int g = 0; g < 16; ++g) {
        int d0 = dp[g * 256 + tb];
        int d1 = dp[g * 256 + 128 + tb];
        vf4 v0 = e4[d0 * 2 + h];
        vf4 v1 = e4[d1 * 2 + h];
        op[g * 512 + t] = v0;
        op[g * 512 + 256 + t] = v1;
    }
}

// Ledger (single-variable deltas, rounds 5-7): tax+residual ~257 (untouchable),
// K1 4.6 (read floor, done), K2 14.9 (this round's target -> ~6), K3 41.6 (write
// floor, done). Predicted dur ~310 +- 4. If >= 315: K2 is dispatch-fixed ->
// declare practical floor.
extern "C" void kernel_launch(void* const* d_in, const int* in_sizes, int n_in,
                              void* d_out, int out_size, void* d_ws, size_t ws_size,
                              hipStream_t stream) {
    const float* adj = (const float*)d_in[0];
    const int* mask = (const int*)d_in[1];  // jnp bool -> int32 per harness convention
    const float* emb = (const float*)d_in[2];
    // workspace layout: [0, 8 MiB) dist bytes, [8 MiB, 9 MiB) packed adjacency bitset
    u64* distw = (u64*)d_ws;
    u64* gsym = (u64*)((char*)d_ws + (size_t)NB * N * N);  // 8 MiB offset
    k1_pack<<<dim3(36, NB), 256, 0, stream>>>(adj, mask, gsym);
    k2_bfs<<<dim3(NB * 32), 256, 0, stream>>>(gsym, mask, distw);
    k3_expand<<<dim3(2048), 256, 0, stream>>>(distw, emb, (vf4*)d_out);
}

// Round 9
// 318.026 us; speedup vs baseline: 1.0114x; 1.0114x over previous
//
#include <hip/hip_runtime.h>
#include <stdint.h>

typedef unsigned long long u64;
typedef float vf4 __attribute__((ext_vector_type(4)));

#define NB 32
#define N 512
#define MAXD 10
#define NW 8    // u64 words per 512-bit row
#define ST 516  // adjT plane stride in u64: 2-way write banks (free), was 8-way at 512
#define PB 8    // frontier pops per batch: 64 independent ds_read_b64 in flight

// ---------------- K1: binarize + symmetrize + mask -> packed bitset (bit-domain) ----------------
// 4.6 us measured (round-7 delta) ~= 32 MiB read floor. DONE.
__global__ __launch_bounds__(256) void k1_pack(const float* __restrict__ adj,
                                               const int* __restrict__ mask,
                                               u64* __restrict__ gsym) {
    __shared__ u64 pa[64];   // packed bits of A(i0+r, j0+c): bit c of pa[r]
    __shared__ u64 pb[64];   // packed bits of A(j0+r, i0+c)
    __shared__ u64 mwIJ[2];  // packed node-mask words for row-blocks ti, tj
    int p = blockIdx.x;
    int b = blockIdx.y;
    int ti = 0;
    while (p >= 8 - ti) { p -= 8 - ti; ++ti; }
    int tj = ti + p;
    int i0 = ti * 64, j0 = tj * 64;
    int t = threadIdx.x, wave = t >> 6, lane = t & 63;
    const float* Ab = adj + (size_t)b * N * N;
    // phase 1: ballot-pack. wave w handles rows w*16..w*16+15 of both tiles.
    #pragma unroll 4
    for (int s = 0; s < 16; ++s) {
        int r = wave * 16 + s;
        bool ba = Ab[(size_t)(i0 + r) * N + j0 + lane] > 0.5f;   // 256 B coalesced
        u64 wa = __ballot(ba);
        bool bb = Ab[(size_t)(j0 + r) * N + i0 + lane] > 0.5f;
        u64 wb = __ballot(bb);
        if (lane == 0) { pa[r] = wa; pb[r] = wb; }
    }
    if (wave < 2) {  // packed mask words (node_mask arrives as int32)
        u64 m = __ballot(mask[b * N + (wave == 0 ? i0 : j0) + lane] != 0);
        if (lane == 0) mwIJ[wave] = m;
    }
    __syncthreads();

    if (wave < 2) {
        // wave0 -> S(ti,tj) = pa | pb^T ; wave1 -> S(tj,ti) = pb | pa^T
        u64 x = (wave == 0) ? pb[lane] : pa[lane];
        // 64x64 bit transpose across the wave: recursive block swap, 6 stages.
        const u64 Hm[6] = {0xFFFFFFFF00000000ULL, 0xFFFF0000FFFF0000ULL,
                           0xFF00FF00FF00FF00ULL, 0xF0F0F0F0F0F0F0F0ULL,
                           0xCCCCCCCCCCCCCCCCULL, 0xAAAAAAAAAAAAAAAAULL};
        #pragma unroll
        for (int k = 0; k < 6; ++k) {
            int j = 32 >> k;
            u64 H = Hm[k];
            u64 y = (u64)__shfl_xor((unsigned long long)x, j);
            x = ((lane & j) == 0) ? ((x & ~H) | ((y << j) & H))
                                  : ((x & H) | ((y >> j) & ~H));
        }
        u64 own  = (wave == 0) ? pa[lane] : pb[lane];
        u64 mrow = mwIJ[wave];           // validity of this output row block
        u64 mcol = mwIJ[wave ^ 1];       // packed mask of the column block
        u64 outw = (own | x) & (((mrow >> lane) & 1) ? mcol : 0ULL);
        size_t row = (size_t)b * N + (wave == 0 ? i0 : j0) + lane;
        int wt = (wave == 0) ? tj : ti;
        gsym[row * NW + wt] = outw;      // diagonal pairs: identical double write, benign
    }
}

// spread 8 bits -> u64 of 8 bytes each 0/1
__device__ __forceinline__ u64 spread8(unsigned b) {
    u64 x = (u64)(b * 0x01010101u);
    x |= x << 32;                       // broadcast byte to all 8 byte lanes
    x &= 0x8040201008040201ULL;         // byte i keeps bit i
    x += 0x7f7f7f7f7f7f7f7fULL;         // bit7 of byte i = (bit i was set); no cross-byte carry
    return (x >> 7) & 0x0101010101010101ULL;
}

// ---------------- K2: bitset-BFS -> dist bytes in global ws (round-7 version, REVERTED) ----------------
// 256 blocks x 64 sources. Round-8's 1024-block/4-blocks-per-CU variant tested the
// "latency/occupancy-bound" theory and FALSIFIED it (+3.4 us): K2's ~14.9 us is
// staging + phase-serialization + fixed overheads, near its structural floor.
__global__ __launch_bounds__(256) void k2_bfs(const u64* __restrict__ gsym,
                                              const int* __restrict__ mask,
                                              u64* __restrict__ distw) {
    __shared__ u64 adjT[NW * ST];     // 33 KB, plane-major [w][j], padded stride
    __shared__ u64 outB[64 * 65];     // packed dist bytes, pad 65 breaks stride-128
    int blk = blockIdx.x;
    int b = blk >> 3;
    int r0 = (blk & 7) * 64;
    int t = threadIdx.x;
    const u64* gs = gsym + (size_t)b * N * NW;
    for (int q = t; q < N * NW; q += 256) {
        u64 w = gs[q];                           // coalesced global read
        adjT[(q & 7) * ST + (q >> 3)] = w;       // transpose; padded stride: 2-way banks
    }
    __syncthreads();

    if (t < 64) {
        int i = r0 + t;
        bool mi = mask[b * N + i] != 0;
        u64 c0[NW], c1[NW], c2[NW], c3[NW];
        #pragma unroll
        for (int w = 0; w < NW; ++w) { c0[w] = 0; c1[w] = 0; c2[w] = 0; c3[w] = 0; }

        if (mi) {
            u64 reach[NW] = {};
            u64 frontier[NW] = {};
            reach[i >> 6] = 1ULL << (i & 63);
            #pragma unroll
            for (int w = 0; w < NW; ++w) frontier[w] = reach[w];
            bool active = true;
            for (int k = 0; k <= MAXD; ++k) {
                // c += ~reach  (bit-sliced increment, 4-bit, max value 11)
                u64 nr_any = 0;
                #pragma unroll
                for (int w = 0; w < NW; ++w) {
                    u64 u = ~reach[w];
                    nr_any |= u;
                    u64 t0 = c0[w] & u; c0[w] ^= u;
                    u64 t1 = c1[w] & t0; c1[w] ^= t0;
                    u64 t2 = c2[w] & t1; c2[w] ^= t1;
                    c3[w] ^= t2;
                }
                if (nr_any == 0) break;   // reach full: all remaining increments no-op
                if (k == MAXD) break;
                if (active) {
                    u64 acc[NW] = {};
                    bool sat = false;
                    for (int w = 0; w < NW && !sat; ++w) {
                        u64 f = frontier[w];
                        while (f && !sat) {
                            // batched pops: up to PB bits, 64 independent ds_read_b64, one check
                            int jlast = w << 6;
                            #pragma unroll
                            for (int u = 0; u < PB; ++u) {
                                int j = f ? ((w << 6) + __builtin_ctzll(f)) : jlast;
                                jlast = j;
                                f &= f - 1;                  // stays 0 once empty
                                #pragma unroll
                                for (int e = 0; e < NW; ++e) acc[e] |= adjT[e * ST + j];
                            }
                            u64 all = acc[0];
                            #pragma unroll
                            for (int e = 1; e < NW; ++e) all &= acc[e];
                            sat = (all == ~0ULL);            // union saturated: exact
                        }
                    }
                    bool any = false;
                    #pragma unroll
                    for (int w = 0; w < NW; ++w) {
                        u64 nf = acc[w] & ~reach[w];
                        frontier[w] = nf;
                        reach[w] |= nf;
                        any = any || (nf != 0);
                    }
                    active = any;
                }
            }
        } else {
            // invalid source row: all distances = 11 = 0b1011
            #pragma unroll
            for (int w = 0; w < NW; ++w) { c0[w] = ~0ULL; c1[w] = ~0ULL; c3[w] = ~0ULL; }
        }

        // expand bit-sliced counters -> dist bytes (8 per u64) into LDS
        #pragma unroll
        for (int w = 0; w < NW; ++w) {
            #pragma unroll
            for (int h = 0; h < 8; ++h) {
                unsigned b0 = (unsigned)(c0[w] >> (8 * h)) & 0xFF;
                unsigned b1 = (unsigned)(c1[w] >> (8 * h)) & 0xFF;
                unsigned b2 = (unsigned)(c2[w] >> (8 * h)) & 0xFF;
                unsigned b3 = (unsigned)(c3[w] >> (8 * h)) & 0xFF;
                outB[t * 65 + w * 8 + h] =
                    spread8(b0) | (spread8(b1) << 1) | (spread8(b2) << 2) | (spread8(b3) << 3);
            }
        }
    }
    __syncthreads();

    // all 4 waves: store 64 rows x 64 u64 of dist bytes, fully coalesced
    u64* dp = distw + ((size_t)(b * N + r0)) * 64;  // 64 u64 words per 512-byte row
    for (int q = t; q < 64 * 64; q += 256) {
        dp[q] = outB[(q >> 6) * 65 + (q & 63)];
    }
}

// ---------------- K3: pure streaming expansion dist byte -> 2x vf4 ----------------
// UNCHANGED — proven at the 6.3 TB/s write roofline (41.6 us, probe rounds 3+4).
__global__ __launch_bounds__(256) void k3_expand(const u64* __restrict__ distw,
                                                 const float* __restrict__ emb,
                                                 vf4* __restrict__ out4) {
    __shared__ vf4 e4[(MAXD + 2) * 2];
    int t = threadIdx.x;
    if (t < (MAXD + 2) * 2) e4[t] = ((const vf4*)emb)[t];
    __syncthreads();
    const unsigned char* __restrict__ db = (const unsigned char*)distw;
    size_t dbase = (size_t)blockIdx.x * 4096;     // dist bytes per block
    const unsigned char* dp = db + dbase;
    vf4* op = out4 + dbase * 2;
    int h = t & 1;
    int tb = t >> 1;
    #pragma unroll 8
    for (int g = 0; g < 16; ++g) {
        int d0 = dp[g * 256 + tb];
        int d1 = dp[g * 256 + 128 + tb];
        vf4 v0 = e4[d0 * 2 + h];
        vf4 v1 = e4[d1 * 2 + h];
        op[g * 512 + t] = v0;
        op[g * 512 + 256 + t] = v1;
    }
}

// TERMINAL CONFIG (revert to round-7 best, 318.16 us). Session ledger:
//   harness tax in timed window  ~238.5 us  (1-GiB poison fills @6.3 TB/s; untouchable)
//   K1 bit-domain pack             4.6 us   (32 MiB read floor)
//   K2 bitset-BFS                ~14.9 us   (occupancy theory falsified in r8; near structural floor)
//   K3 expansion                  41.6 us   (264 MiB @ 6.3 TB/s write roofline)
//   residual (bubbles/est. slack) ~18 us
// Controllable portion is within a few % of its memory floor; 351.4 -> 318.2 overall.
extern "C" void kernel_launch(void* const* d_in, const int* in_sizes, int n_in,
                              void* d_out, int out_size, void* d_ws, size_t ws_size,
                              hipStream_t stream) {
    const float* adj = (const float*)d_in[0];
    const int* mask = (const int*)d_in[1];  // jnp bool -> int32 per harness convention
    const float* emb = (const float*)d_in[2];
    // workspace layout: [0, 8 MiB) dist bytes, [8 MiB, 9 MiB) packed adjacency bitset
    u64* distw = (u64*)d_ws;
    u64* gsym = (u64*)((char*)d_ws + (size_t)NB * N * N);  // 8 MiB offset
    k1_pack<<<dim3(36, NB), 256, 0, stream>>>(adj, mask, gsym);
    k2_bfs<<<dim3(NB * 8), 256, 0, stream>>>(gsym, mask, distw);
    k3_expand<<<dim3(2048), 256, 0, stream>>>(distw, emb, (vf4*)d_out);
}